// Round 7
// baseline (633.355 us; speedup 1.0000x reference)
//
#include <hip/hip_runtime.h>
#include <cstddef>
#include <cstdint>

// ---------------------------------------------------------------------------
// SAGE_89429809037918: pre-Linear(128->128) -> SAGEConv(128->256)+ReLU
//   -> SAGEConv(256->256)+ReLU -> SAGEConv(256->256) -> row L2-normalize.
// R12: co-scheduling. Gather is fabric-bound (65us, MFMA 0%, VALU 31%) ->
//      an entire GPU of compute idles during 165us of gather. Split each
//      layer's GEMM: Y = h@W_r + b (independent of gather) runs INSIDE the
//      gather dispatch as a block-range branch (GEMM blocks first); then
//      h_next = act(agg@W_l + Y) as a single-pass wide GEMM. Y kept fp32
//      (identical numerics, only add order changes). Also fused: deg∥prep,
//      fill∥pre-GEMM. 17 -> 12 dispatches.
//      Predict: fused gather dispatches ~68-75us (WRITE 26->77MB), total
//      497 -> ~450. If fused gather >=85us, occupancy drop hurt -> revert.
// ---------------------------------------------------------------------------

typedef __attribute__((ext_vector_type(8))) short short8;   // 8 bf16 = 4 VGPR
typedef __attribute__((ext_vector_type(4))) float f32x4;

__device__ __forceinline__ unsigned rne_bf16(float f) {
    unsigned b = __float_as_uint(f);
    return (b + 0x7fffu + ((b >> 16) & 1u)) >> 16;
}
__device__ __forceinline__ float bf16_lo(unsigned u) { return __uint_as_float(u << 16); }
__device__ __forceinline__ float bf16_hi(unsigned u) { return __uint_as_float(u & 0xffff0000u); }

// 16B global->LDS stage (linear LDS dest = wave-uniform base + lane*16;
// per-lane source address carries the swizzle).
__device__ __forceinline__ void stage16(const void* g, unsigned short* ldsbase,
                                        int lane) {
#if __has_builtin(__builtin_amdgcn_global_load_lds)
    (void)lane;
    __builtin_amdgcn_global_load_lds(
        (const __attribute__((address_space(1))) unsigned int*)g,
        (__attribute__((address_space(3))) unsigned int*)ldsbase, 16, 0, 0);
#else
    *(uint4*)(ldsbase + (size_t)lane * 8) = *(const uint4*)g;
#endif
}

// ---------------- scan helpers (unchanged) ---------------------------------

__global__ __launch_bounds__(256) void bsum_kernel(const int* __restrict__ deg,
                                                   int* __restrict__ bsum, int n) {
    int i = blockIdx.x * 256 + threadIdx.x;
    int v = (i < n) ? deg[i] : 0;
#pragma unroll
    for (int s = 32; s > 0; s >>= 1) v += __shfl_down(v, s);
    __shared__ int ws[4];
    int lane = threadIdx.x & 63, w = threadIdx.x >> 6;
    if (lane == 0) ws[w] = v;
    __syncthreads();
    if (threadIdx.x == 0) bsum[blockIdx.x] = ws[0] + ws[1] + ws[2] + ws[3];
}

__global__ __launch_bounds__(256) void bscan_kernel(const int* __restrict__ bsum,
                                                    int* __restrict__ boff,
                                                    int* __restrict__ off,
                                                    int nb, int n, int E) {
    int t = threadIdx.x;
    int v = (t < nb) ? bsum[t] : 0;
    int incl = v;
#pragma unroll
    for (int s = 1; s < 64; s <<= 1) {
        int u = __shfl_up(incl, s);
        if ((t & 63) >= s) incl += u;
    }
    __shared__ int ws[4];
    int lane = t & 63, w = t >> 6;
    if (lane == 63) ws[w] = incl;
    __syncthreads();
    int woff = 0;
    for (int j = 0; j < w; ++j) woff += ws[j];
    if (t < nb) boff[t] = woff + incl - v;
    if (t == 0) off[n] = E;
}

__global__ __launch_bounds__(256) void scan_kernel(const int* __restrict__ deg,
                                                   const int* __restrict__ boff,
                                                   int* __restrict__ off,
                                                   float* __restrict__ inv, int n) {
    int i = blockIdx.x * 256 + threadIdx.x;
    int v = (i < n) ? deg[i] : 0;
    int incl = v;
#pragma unroll
    for (int s = 1; s < 64; s <<= 1) {
        int u = __shfl_up(incl, s);
        if ((threadIdx.x & 63) >= s) incl += u;
    }
    __shared__ int ws[4];
    int lane = threadIdx.x & 63, w = threadIdx.x >> 6;
    if (lane == 63) ws[w] = incl;
    __syncthreads();
    int woff = 0;
    for (int j = 0; j < w; ++j) woff += ws[j];
    if (i < n) {
        off[i] = boff[blockIdx.x] + woff + incl - v;
        inv[i] = 1.0f / fmaxf((float)v, 1.0f);
    }
}

// ---------------- fatA: prep (x->bf16, W->bf16^T) ∥ deg histogram ----------

__global__ __launch_bounds__(256) void fatA(
    const float* __restrict__ x, uint2* __restrict__ xb, int n4, int XB, int PB,
    const float* __restrict__ pre_W, const float* __restrict__ W1_l,
    const float* __restrict__ W1_r, const float* __restrict__ W2_l,
    const float* __restrict__ W2_r, const float* __restrict__ W3_l,
    const float* __restrict__ W3_r,
    unsigned short* __restrict__ WT0, unsigned short* __restrict__ WT1,
    unsigned short* __restrict__ WT2, unsigned short* __restrict__ WT3,
    unsigned short* __restrict__ WT4, unsigned short* __restrict__ WT5,
    unsigned short* __restrict__ WT6,
    const int* __restrict__ dst, int* __restrict__ deg, int E) {
    if (blockIdx.x >= (unsigned)PB) {  // ---- deg histogram ----
        int e = (blockIdx.x - PB) * 256 + threadIdx.x;
        if (e < E) atomicAdd(&deg[dst[e]], 1);
        return;
    }
    if (blockIdx.x < (unsigned)XB) {   // ---- xconv ----
        int i = blockIdx.x * 256 + threadIdx.x;
        if (i >= n4) return;
        float4 v = ((const float4*)x)[i];
        uint2 o;
        o.x = rne_bf16(v.x) | (rne_bf16(v.y) << 16);
        o.y = rne_bf16(v.z) | (rne_bf16(v.w) << 16);
        xb[i] = o;
        return;
    }
    int idx = (blockIdx.x - XB) * 256 + threadIdx.x;  // ---- wprep ----
    if (idx < 16384) {
        int k = idx >> 7, n = idx & 127;
        WT0[n * 128 + k] = (unsigned short)rne_bf16(pre_W[idx]);
        return;
    }
    idx -= 16384;
    if (idx < 32768) {
        int k = idx >> 8, n = idx & 255;
        WT1[n * 128 + k] = (unsigned short)rne_bf16(W1_l[idx]);
        return;
    }
    idx -= 32768;
    if (idx < 32768) {
        int k = idx >> 8, n = idx & 255;
        WT2[n * 128 + k] = (unsigned short)rne_bf16(W1_r[idx]);
        return;
    }
    idx -= 32768;
    if (idx < 65536) {
        int k = idx >> 8, n = idx & 255;
        WT3[n * 256 + k] = (unsigned short)rne_bf16(W2_l[idx]);
        return;
    }
    idx -= 65536;
    if (idx < 65536) {
        int k = idx >> 8, n = idx & 255;
        WT4[n * 256 + k] = (unsigned short)rne_bf16(W2_r[idx]);
        return;
    }
    idx -= 65536;
    if (idx < 65536) {
        int k = idx >> 8, n = idx & 255;
        WT5[n * 256 + k] = (unsigned short)rne_bf16(W3_l[idx]);
        return;
    }
    idx -= 65536;
    if (idx < 65536) {
        int k = idx >> 8, n = idx & 255;
        WT6[n * 256 + k] = (unsigned short)rne_bf16(W3_r[idx]);
    }
}

// ---------------- 128x128-tile GEMM body (256 thr, 4 waves 2x2) ------------
// A [M,K] bf16, WT [Nn,K] bf16. If Yout: write fp32 Y=acc+bias (no act).
// Else write bf16 outb=acc+bias. Swizzled LDS (slot s of row r <- chunk
// s^(r&7)); fragment reads conflict-free.
__device__ __forceinline__ void gemm128_body(
    unsigned short* As, unsigned short* Bs,
    const unsigned short* __restrict__ A, const unsigned short* __restrict__ WT,
    const float* __restrict__ bias, float* __restrict__ Yout,
    unsigned short* __restrict__ outb, int M, int K, int Nn, int m0, int n0) {
    const int t = threadIdx.x;
    const int lane = t & 63;
    const int w = t >> 6;
    const int wm = w >> 1, wn = w & 1;

    f32x4 acc[4][4];
#pragma unroll
    for (int i = 0; i < 4; ++i)
#pragma unroll
        for (int j = 0; j < 4; ++j) acc[i][j] = (f32x4){0.f, 0.f, 0.f, 0.f};

    for (int k0 = 0; k0 < K; k0 += 64) {
#pragma unroll
        for (int r = 0; r < 4; ++r) {
            int p = r * 256 + t;
            int row = p >> 3, slot = p & 7;
            int c = slot ^ (row & 7);
            int gm = m0 + row;
            if (gm >= M) gm = M - 1;
            uint4 va = *(const uint4*)(A + (size_t)gm * K + k0 + c * 8);
            uint4 vb = *(const uint4*)(WT + (size_t)(n0 + row) * K + k0 + c * 8);
            *(uint4*)&As[(size_t)p * 8] = va;
            *(uint4*)&Bs[(size_t)p * 8] = vb;
        }
        __syncthreads();
#pragma unroll
        for (int kk = 0; kk < 2; ++kk) {
            short8 af[4], bfr[4];
            int ac = kk * 4 + (lane >> 4);
#pragma unroll
            for (int i = 0; i < 4; ++i) {
                int arow = wm * 64 + i * 16 + (lane & 15);
                af[i] = *(const short8*)&As[arow * 64 + ((ac ^ (arow & 7)) << 3)];
                int brow = wn * 64 + i * 16 + (lane & 15);
                bfr[i] = *(const short8*)&Bs[brow * 64 + ((ac ^ (brow & 7)) << 3)];
            }
#pragma unroll
            for (int mi = 0; mi < 4; ++mi)
#pragma unroll
                for (int ni = 0; ni < 4; ++ni)
                    acc[mi][ni] = __builtin_amdgcn_mfma_f32_16x16x32_bf16(
                        af[mi], bfr[ni], acc[mi][ni], 0, 0, 0);
        }
        __syncthreads();
    }

#pragma unroll
    for (int ni = 0; ni < 4; ++ni) {
        int n = n0 + wn * 64 + ni * 16 + (lane & 15);
        float bv = bias[n];
#pragma unroll
        for (int mi = 0; mi < 4; ++mi) {
            int mbase = m0 + wm * 64 + mi * 16 + ((lane >> 4) << 2);
#pragma unroll
            for (int r = 0; r < 4; ++r) {
                int m = mbase + r;
                if (m >= M) continue;
                float v = acc[mi][ni][r] + bv;
                if (Yout) Yout[(size_t)m * Nn + n] = v;
                else      outb[(size_t)m * Nn + n] = (unsigned short)rne_bf16(v);
            }
        }
    }
}

// ---------------- fatB: pre-GEMM (h0 = x@preW + b) ∥ fill ------------------

__global__ __launch_bounds__(256) void fatB(
    const unsigned short* __restrict__ xb, const unsigned short* __restrict__ WT0,
    const float* __restrict__ pre_b, unsigned short* __restrict__ h0b, int M,
    int GB,
    const int* __restrict__ src, const int* __restrict__ dst,
    const int* __restrict__ off, int* __restrict__ deg,
    int* __restrict__ ssrc, int E) {
    __shared__ __align__(16) unsigned short As[128 * 64];
    __shared__ __align__(16) unsigned short Bs[128 * 64];
    if (blockIdx.x < (unsigned)GB) {
        gemm128_body(As, Bs, xb, WT0, pre_b, nullptr, h0b, M, 128, 128,
                     blockIdx.x * 128, 0);
        return;
    }
    int e = (blockIdx.x - GB) * 256 + threadIdx.x;
    if (e >= E) return;
    int d = dst[e];
    int pos = off[d] + atomicSub(&deg[d], 1) - 1;
    ssrc[pos] = src[e];
}

// ---------------- fused Y-GEMM ∥ gather ------------------------------------
// Blocks [0, GB): Y = h@W_rT + bias (fp32, Nn=256, GB = MT*2).
// Blocks [GB, GB+AG): R7 gather on h (template D), agg bf16 out.

template <int D>
__global__ __launch_bounds__(256) void fat_gy(
    const unsigned short* __restrict__ h, const unsigned short* __restrict__ WrT,
    const float* __restrict__ bias, float* __restrict__ Yf, int M, int K, int GB,
    const int* __restrict__ off, const int* __restrict__ ssrc,
    const float* __restrict__ inv, unsigned short* __restrict__ agg, int n) {
    __shared__ __align__(16) unsigned short As[128 * 64];
    __shared__ __align__(16) unsigned short Bs[128 * 64];
    if (blockIdx.x < (unsigned)GB) {
        int p = blockIdx.x;
        gemm128_body(As, Bs, h, WrT, bias, Yf, nullptr, M, K, 256,
                     (p >> 1) * 128, (p & 1) * 128);
        return;
    }
    int node = (blockIdx.x - GB) * 4 + (threadIdx.x >> 6);
    if (node >= n) return;
    int lane = threadIdx.x & 63;
    int beg = off[node], end = off[node + 1];
    float sc = inv[node];

    if (D == 256) {
        const int half = lane >> 5;
        const int sub  = lane & 31;
        const unsigned short* col = h + (sub << 3);
        float a[8] = {0, 0, 0, 0, 0, 0, 0, 0};
        float b[8] = {0, 0, 0, 0, 0, 0, 0, 0};
        int k = beg;
        for (; k + 3 < end; k += 4) {
            int s0 = ssrc[k + half];
            int s1 = ssrc[k + 2 + half];
            uint4 u = *(const uint4*)(col + (size_t)s0 * 256);
            uint4 v = *(const uint4*)(col + (size_t)s1 * 256);
            a[0] += bf16_lo(u.x); a[1] += bf16_hi(u.x);
            a[2] += bf16_lo(u.y); a[3] += bf16_hi(u.y);
            a[4] += bf16_lo(u.z); a[5] += bf16_hi(u.z);
            a[6] += bf16_lo(u.w); a[7] += bf16_hi(u.w);
            b[0] += bf16_lo(v.x); b[1] += bf16_hi(v.x);
            b[2] += bf16_lo(v.y); b[3] += bf16_hi(v.y);
            b[4] += bf16_lo(v.z); b[5] += bf16_hi(v.z);
            b[6] += bf16_lo(v.w); b[7] += bf16_hi(v.w);
        }
        for (; k < end; k += 2) {
            int e = k + half;
            if (e < end) {
                uint4 u = *(const uint4*)(col + (size_t)ssrc[e] * 256);
                a[0] += bf16_lo(u.x); a[1] += bf16_hi(u.x);
                a[2] += bf16_lo(u.y); a[3] += bf16_hi(u.y);
                a[4] += bf16_lo(u.z); a[5] += bf16_hi(u.z);
                a[6] += bf16_lo(u.w); a[7] += bf16_hi(u.w);
            }
        }
#pragma unroll
        for (int i = 0; i < 8; ++i) a[i] += b[i];
#pragma unroll
        for (int i = 0; i < 8; ++i) a[i] += __shfl_xor(a[i], 32);
        if (half == 0) {
#pragma unroll
            for (int i = 0; i < 8; ++i) a[i] *= sc;
            uint4 o;
            o.x = rne_bf16(a[0]) | (rne_bf16(a[1]) << 16);
            o.y = rne_bf16(a[2]) | (rne_bf16(a[3]) << 16);
            o.z = rne_bf16(a[4]) | (rne_bf16(a[5]) << 16);
            o.w = rne_bf16(a[6]) | (rne_bf16(a[7]) << 16);
            *(uint4*)(agg + (size_t)node * 256 + (sub << 3)) = o;
        }
    } else {  // D == 128
        const int q   = lane >> 4;
        const int sub = lane & 15;
        const unsigned short* col = h + (sub << 3);
        float a[8] = {0, 0, 0, 0, 0, 0, 0, 0};
        float b[8] = {0, 0, 0, 0, 0, 0, 0, 0};
        int k = beg;
        for (; k + 7 < end; k += 8) {
            int s0 = ssrc[k + q];
            int s1 = ssrc[k + 4 + q];
            uint4 u = *(const uint4*)(col + (size_t)s0 * 128);
            uint4 v = *(const uint4*)(col + (size_t)s1 * 128);
            a[0] += bf16_lo(u.x); a[1] += bf16_hi(u.x);
            a[2] += bf16_lo(u.y); a[3] += bf16_hi(u.y);
            a[4] += bf16_lo(u.z); a[5] += bf16_hi(u.z);
            a[6] += bf16_lo(u.w); a[7] += bf16_hi(u.w);
            b[0] += bf16_lo(v.x); b[1] += bf16_hi(v.x);
            b[2] += bf16_lo(v.y); b[3] += bf16_hi(v.y);
            b[4] += bf16_lo(v.z); b[5] += bf16_hi(v.z);
            b[6] += bf16_lo(v.w); b[7] += bf16_hi(v.w);
        }
        for (; k < end; k += 4) {
            int e = k + q;
            if (e < end) {
                uint4 u = *(const uint4*)(col + (size_t)ssrc[e] * 128);
                a[0] += bf16_lo(u.x); a[1] += bf16_hi(u.x);
                a[2] += bf16_lo(u.y); a[3] += bf16_hi(u.y);
                a[4] += bf16_lo(u.z); a[5] += bf16_hi(u.z);
                a[6] += bf16_lo(u.w); a[7] += bf16_hi(u.w);
            }
        }
#pragma unroll
        for (int i = 0; i < 8; ++i) a[i] += b[i];
#pragma unroll
        for (int i = 0; i < 8; ++i) a[i] += __shfl_xor(a[i], 16);
#pragma unroll
        for (int i = 0; i < 8; ++i) a[i] += __shfl_xor(a[i], 32);
        if (q == 0) {
#pragma unroll
            for (int i = 0; i < 8; ++i) a[i] *= sc;
            uint4 o;
            o.x = rne_bf16(a[0]) | (rne_bf16(a[1]) << 16);
            o.y = rne_bf16(a[2]) | (rne_bf16(a[3]) << 16);
            o.z = rne_bf16(a[4]) | (rne_bf16(a[5]) << 16);
            o.w = rne_bf16(a[6]) | (rne_bf16(a[7]) << 16);
            *(uint4*)(agg + (size_t)node * 128 + (sub << 3)) = o;
        }
    }
}

// ---------------- l-GEMM: out = act(agg@W_lT + Y) --------------------------
// BM=128, BN=256, 512 thr (8 waves 2x4), single pass. Y fp32 added in
// epilogue (bias already in Y). outb: bf16 (+relu). outf: fp32 + fused
// row L2-normalize.
__global__ __launch_bounds__(512) void gemm_lw(
    const unsigned short* __restrict__ A, const unsigned short* __restrict__ WlT,
    const float* __restrict__ Yf,
    unsigned short* __restrict__ outb, float* __restrict__ outf,
    int M, int K, int relu) {
    __shared__ __align__(16) unsigned short As[128 * 64];
    __shared__ __align__(16) unsigned short Bs[256 * 64];
    __shared__ float rs[128][4];

    const int t = threadIdx.x;
    const int lane = t & 63;
    const int w8 = t >> 6;
    const int wm = w8 >> 2, wn = w8 & 3;
    const int m0 = blockIdx.x * 128;

    f32x4 acc[4][4];
#pragma unroll
    for (int i = 0; i < 4; ++i)
#pragma unroll
        for (int j = 0; j < 4; ++j) acc[i][j] = (f32x4){0.f, 0.f, 0.f, 0.f};

    for (int k0 = 0; k0 < K; k0 += 64) {
#pragma unroll
        for (int i = 0; i < 2; ++i) {
            int base = (w8 * 2 + i) * 64;
            int p = base + lane;
            int row = p >> 3, slot = p & 7;
            int c = slot ^ (row & 7);
            int gm = m0 + row;
            if (gm >= M) gm = M - 1;
            stage16(A + (size_t)gm * K + k0 + c * 8, &As[(size_t)base * 8], lane);
        }
#pragma unroll
        for (int i = 0; i < 4; ++i) {
            int base = (w8 * 4 + i) * 64;
            int p = base + lane;
            int row = p >> 3, slot = p & 7;
            int c = slot ^ (row & 7);
            stage16(WlT + (size_t)row * K + k0 + c * 8, &Bs[(size_t)base * 8], lane);
        }
        __syncthreads();
#pragma unroll
        for (int kk = 0; kk < 2; ++kk) {
            short8 af[4], bfr[4];
            int ac = kk * 4 + (lane >> 4);
#pragma unroll
            for (int i = 0; i < 4; ++i) {
                int arow = wm * 64 + i * 16 + (lane & 15);
                af[i] = *(const short8*)&As[arow * 64 + ((ac ^ (arow & 7)) << 3)];
                int brow = wn * 64 + i * 16 + (lane & 15);
                bfr[i] = *(const short8*)&Bs[brow * 64 + ((ac ^ (brow & 7)) << 3)];
            }
#pragma unroll
            for (int mi = 0; mi < 4; ++mi)
#pragma unroll
                for (int ni = 0; ni < 4; ++ni)
                    acc[mi][ni] = __builtin_amdgcn_mfma_f32_16x16x32_bf16(
                        af[mi], bfr[ni], acc[mi][ni], 0, 0, 0);
        }
        __syncthreads();
    }

    // add Y (holds x-side partial + bias)
#pragma unroll
    for (int ni = 0; ni < 4; ++ni) {
        int n = wn * 64 + ni * 16 + (lane & 15);
#pragma unroll
        for (int mi = 0; mi < 4; ++mi) {
            int mbase = m0 + wm * 64 + mi * 16 + ((lane >> 4) << 2);
#pragma unroll
            for (int r = 0; r < 4; ++r) {
                int m = mbase + r;
                if (m < M) acc[mi][ni][r] += Yf[(size_t)m * 256 + n];
            }
        }
    }

    if (outb) {
#pragma unroll
        for (int ni = 0; ni < 4; ++ni) {
            int n = wn * 64 + ni * 16 + (lane & 15);
#pragma unroll
            for (int mi = 0; mi < 4; ++mi) {
                int mbase = m0 + wm * 64 + mi * 16 + ((lane >> 4) << 2);
#pragma unroll
                for (int r = 0; r < 4; ++r) {
                    int m = mbase + r;
                    if (m >= M) continue;
                    float v = acc[mi][ni][r];
                    if (relu) v = fmaxf(v, 0.0f);
                    outb[(size_t)m * 256 + n] = (unsigned short)rne_bf16(v);
                }
            }
        }
        return;
    }

    // fp32 out with fused L2 normalize
#pragma unroll
    for (int mi = 0; mi < 4; ++mi) {
#pragma unroll
        for (int r = 0; r < 4; ++r) {
            float p = acc[mi][0][r] * acc[mi][0][r] + acc[mi][1][r] * acc[mi][1][r] +
                      acc[mi][2][r] * acc[mi][2][r] + acc[mi][3][r] * acc[mi][3][r];
            p += __shfl_xor(p, 1);
            p += __shfl_xor(p, 2);
            p += __shfl_xor(p, 4);
            p += __shfl_xor(p, 8);
            if ((lane & 15) == 0)
                rs[wm * 64 + mi * 16 + ((lane >> 4) << 2) + r][wn] = p;
        }
    }
    __syncthreads();
#pragma unroll
    for (int mi = 0; mi < 4; ++mi) {
        int mbase = m0 + wm * 64 + mi * 16 + ((lane >> 4) << 2);
        int lrow = wm * 64 + mi * 16 + ((lane >> 4) << 2);
#pragma unroll
        for (int r = 0; r < 4; ++r) {
            int m = mbase + r;
            if (m >= M) continue;
            float s = rs[lrow + r][0] + rs[lrow + r][1] + rs[lrow + r][2] + rs[lrow + r][3];
            float sc = 1.0f / fmaxf(sqrtf(s), 1e-12f);
#pragma unroll
            for (int ni = 0; ni < 4; ++ni) {
                int n = wn * 64 + ni * 16 + (lane & 15);
                outf[(size_t)m * 256 + n] = acc[mi][ni][r] * sc;
            }
        }
    }
}

extern "C" void kernel_launch(void* const* d_in, const int* in_sizes, int n_in,
                              void* d_out, int out_size, void* d_ws, size_t ws_size,
                              hipStream_t stream) {
    const int N = 50000;
    const int E = 800000;
    const int NB = (N + 255) / 256;

    const float* x     = (const float*)d_in[0];
    const int*   ei    = (const int*)d_in[1];
    const float* pre_W = (const float*)d_in[2];
    const float* pre_b = (const float*)d_in[3];
    const float* W1_l  = (const float*)d_in[4];
    const float* b1    = (const float*)d_in[5];
    const float* W1_r  = (const float*)d_in[6];
    const float* W2_l  = (const float*)d_in[7];
    const float* b2    = (const float*)d_in[8];
    const float* W2_r  = (const float*)d_in[9];
    const float* W3_l  = (const float*)d_in[10];
    const float* b3    = (const float*)d_in[11];
    const float* W3_r  = (const float*)d_in[12];
    float* out = (float*)d_out;

    const int* src = ei;
    const int* dst = ei + E;

    // ---- workspace layout ----
    int* deg  = (int*)d_ws;
    int* off  = deg + N;
    int* bsum = off + N + 1;
    int* boff = bsum + 256;
    int* ssrc = boff + 256;
    size_t int_words = (size_t)2 * N + 1 + 512 + E;
    int_words = (int_words + 3) & ~(size_t)3;  // 16B align

    float* inv = (float*)d_ws + int_words;
    float* Yf  = inv + N;                      // N x 256 fp32
    unsigned short* us = (unsigned short*)(Yf + (size_t)N * 256);

    unsigned short* xb  = us;                 us += (size_t)N * 128;
    unsigned short* WT0 = us;                 us += 16384;
    unsigned short* WT1 = us;                 us += 32768;
    unsigned short* WT2 = us;                 us += 32768;
    unsigned short* WT3 = us;                 us += 65536;
    unsigned short* WT4 = us;                 us += 65536;
    unsigned short* WT5 = us;                 us += 65536;
    unsigned short* WT6 = us;                 us += 65536;
    unsigned short* h0b   = us;               us += (size_t)N * 128;
    unsigned short* agg1b = us;               us += (size_t)N * 128;
    unsigned short* h1b   = us;               us += (size_t)N * 256;
    unsigned short* agg2b = us;               us += (size_t)N * 256;
    unsigned short* h2b   = us;               us += (size_t)N * 256;
    unsigned short* agg3b = us;               us += (size_t)N * 256;

    const int MT = (N + 127) / 128;   // 391
    const int AG = (N + 3) / 4;       // 12500
    const int GB = MT * 2;            // 782 (Y-GEMM blocks, Nn=256)
    const int n4 = N * 128 / 4;       // 1,600,000
    const int XB = (n4 + 255) / 256;  // 6250
    const int WB = (344064 + 255) / 256;  // 1344
    const int PB = XB + WB;           // prep blocks
    const int DB = (E + 255) / 256;   // 3125

    // ---- fatA: converts ∥ deg histogram ----
    hipMemsetAsync(deg, 0, (size_t)N * sizeof(int), stream);
    fatA<<<PB + DB, 256, 0, stream>>>(x, (uint2*)xb, n4, XB, PB,
                                      pre_W, W1_l, W1_r, W2_l, W2_r, W3_l, W3_r,
                                      WT0, WT1, WT2, WT3, WT4, WT5, WT6,
                                      dst, deg, E);
    bsum_kernel<<<NB, 256, 0, stream>>>(deg, bsum, N);
    bscan_kernel<<<1, 256, 0, stream>>>(bsum, boff, off, NB, N, E);
    scan_kernel<<<NB, 256, 0, stream>>>(deg, boff, off, inv, N);

    // ---- fatB: pre-GEMM (h0) ∥ fill ----
    fatB<<<MT + DB, 256, 0, stream>>>(xb, WT0, pre_b, h0b, N, MT,
                                      src, dst, off, deg, ssrc, E);

    // ---- layer 1: [Y1 = h0@W1_r + b1] ∥ gather(h0) ; h1 = relu(agg@W1_l+Y) --
    fat_gy<128><<<GB + AG, 256, 0, stream>>>(h0b, WT2, b1, Yf, N, 128, GB,
                                             off, ssrc, inv, agg1b, N);
    gemm_lw<<<MT, 512, 0, stream>>>(agg1b, WT1, Yf, h1b, nullptr, N, 128, 1);

    // ---- layer 2 ----
    fat_gy<256><<<GB + AG, 256, 0, stream>>>(h1b, WT4, b2, Yf, N, 256, GB,
                                             off, ssrc, inv, agg2b, N);
    gemm_lw<<<MT, 512, 0, stream>>>(agg2b, WT3, Yf, h2b, nullptr, N, 256, 1);

    // ---- layer 3 (no relu) + fused L2 normalize ----
    fat_gy<256><<<GB + AG, 256, 0, stream>>>(h2b, WT6, b3, Yf, N, 256, GB,
                                             off, ssrc, inv, agg3b, N);
    gemm_lw<<<MT, 512, 0, stream>>>(agg3b, WT5, Yf, nullptr, out, N, 256, 0);
}